// Round 22
// baseline (197.477 us; speedup 1.0000x reference)
//
#include <hip/hip_runtime.h>
#include <math.h>

#define NB 64
#define NP 196
#define ND 256
#define NBP (NB * NP)   // 12544

typedef __bf16 v8bf __attribute__((ext_vector_type(8)));
typedef float f32x16 __attribute__((ext_vector_type(16)));
typedef int v8i __attribute__((ext_vector_type(8)));

// ws layout (fast path), bytes:
//   inv1   @ 0        : 12544 f32
//   inv2   @ 50176    : 12544 f32
//   sim12  @ 100352   : 4096  f32
//   t1q    @ 116736   : 98 tiles  x fp8 MX fragment-linear [chunk4][hi2][half2][row128][16B] = 3211264 B
//   t2q    @ 3328000  : 64 panels x fp8 MX fragment-linear [chunk4][hi2][half2][col256][16B] = 4194304 B
//   parts  @ 7522304  : 64*4*196 u64 = 401408 B
//   rmg    @ 7923712  : 98*2*128*64 f32 rowmax partials = 6422528 B
#define WS_T1Q    116736
#define WS_T2Q    3328000
#define WS_PARTS  7522304
#define WS_RMG    7923712
#define WS_NEED   14346240

// ---------------------------------------------------------------------------
// packed (value,index) for argmax with np first-occurrence tie-break
// ---------------------------------------------------------------------------
__device__ __forceinline__ unsigned int fmono(float v) {
    unsigned int u = __float_as_uint(v);
    return (u & 0x80000000u) ? ~u : (u | 0x80000000u);
}
__device__ __forceinline__ unsigned long long packVI(float v, int idx) {
    return ((unsigned long long)fmono(v) << 32) | (unsigned int)(~idx);
}

__device__ __forceinline__ v8i mkop(int4 lo, int4 hi) {
    v8i r;
    r[0] = lo.x; r[1] = lo.y; r[2] = lo.z; r[3] = lo.w;
    r[4] = hi.x; r[5] = hi.y; r[6] = hi.z; r[7] = hi.w;
    return r;
}

// ===========================================================================
// FAST PATH
// ===========================================================================

// Kernel 1: per-row norm -> inv arrays; write normalized FP8 (e4m3) in MX
// fragment-linear layout for K=64 scaled MFMA. Lane L holds k = 4L..4L+3:
//   chunk=(L>>4), hi=(L>>3)&1, half=(L>>2)&1, j0=(L&3)*4.
__global__ __launch_bounds__(256)
void filip_prep8(const float* __restrict__ t1, const float* __restrict__ t2,
                 float* __restrict__ inv1, float* __restrict__ inv2,
                 float* __restrict__ sim12,
                 char* __restrict__ t1q, char* __restrict__ t2q) {
    const int tid = threadIdx.x;
    if (blockIdx.x == 0) {
        float4 z = make_float4(0.f, 0.f, 0.f, 0.f);
        float4* s4 = reinterpret_cast<float4*>(sim12);
        #pragma unroll
        for (int j = 0; j < 4; ++j) s4[tid * 4 + j] = z;
    }
    int id = blockIdx.x * 4 + (tid >> 6);   // 0 .. NBP + NB*256 - 1
    int L = tid & 63;
    int chunk = L >> 4, hi = (L >> 3) & 1, half = (L >> 2) & 1, j0 = (L & 3) * 4;
    if (id < NBP) {
        const float* src = t1 + (size_t)id * ND;
        float4 v = reinterpret_cast<const float4*>(src)[L];
        float ss = v.x * v.x + v.y * v.y + v.z * v.z + v.w * v.w;
        #pragma unroll
        for (int off = 32; off > 0; off >>= 1) ss += __shfl_xor(ss, off, 64);
        float inv = 1.0f / fmaxf(sqrtf(ss), 1e-12f);
        if (L == 0) inv1[id] = inv;
        int w0 = __builtin_amdgcn_cvt_pk_fp8_f32(v.x * inv, v.y * inv, 0, false);
        int w  = __builtin_amdgcn_cvt_pk_fp8_f32(v.z * inv, v.w * inv, w0, true);
        int t = id >> 7, r = id & 127;
        *reinterpret_cast<int*>(t1q + (size_t)t * 32768 + chunk * 8192 + hi * 4096
                                + half * 2048 + r * 16 + j0) = w;
    } else {
        int pid = id - NBP;          // 0..16383
        int b2 = pid >> 8, c = pid & 255;
        char* dst = t2q + (size_t)b2 * 65536 + chunk * 16384 + hi * 8192
                    + half * 4096 + c * 16 + j0;
        if (c < NP) {
            const float* src = t2 + (size_t)(b2 * NP + c) * ND;
            float4 v = reinterpret_cast<const float4*>(src)[L];
            float ss = v.x * v.x + v.y * v.y + v.z * v.z + v.w * v.w;
            #pragma unroll
            for (int off = 32; off > 0; off >>= 1) ss += __shfl_xor(ss, off, 64);
            float inv = 1.0f / fmaxf(sqrtf(ss), 1e-12f);
            if (L == 0) inv2[b2 * NP + c] = inv;
            int w0 = __builtin_amdgcn_cvt_pk_fp8_f32(v.x * inv, v.y * inv, 0, false);
            int w  = __builtin_amdgcn_cvt_pk_fp8_f32(v.z * inv, v.w * inv, w0, true);
            *reinterpret_cast<int*>(dst) = w;
        } else {
            *reinterpret_cast<int*>(dst) = 0;   // fp8 zeros
        }
    }
}

#define BM 128
#define BN 256

#define LOADA(TOFF)                                                          \
    _Pragma("unroll")                                                        \
    for (int c = 0; c < 4; ++c)                                              \
        _Pragma("unroll")                                                    \
        for (int mt = 0; mt < 2; ++mt) {                                     \
            const char* p = Ag + (TOFF) + c * 8192 + mt * 512;               \
            int4 lo = *reinterpret_cast<const int4*>(p);                     \
            int4 h4 = *reinterpret_cast<const int4*>(p + 2048);              \
            aA[c][mt] = mkop(lo, h4);                                        \
        }

#define ZEROACC                                                              \
    _Pragma("unroll")                                                        \
    for (int mt = 0; mt < 2; ++mt)                                           \
        _Pragma("unroll")                                                    \
        for (int nt = 0; nt < 4; ++nt)                                       \
            _Pragma("unroll")                                                \
            for (int r = 0; r < 16; ++r) acc[mt][nt][r] = 0.0f;

#define KLOOP                                                                \
    __builtin_amdgcn_s_setprio(1);                                           \
    _Pragma("unroll")                                                        \
    for (int c = 0; c < 4; ++c) {                                            \
        v8i bfr[4];                                                          \
        _Pragma("unroll")                                                    \
        for (int nt = 0; nt < 4; ++nt) {                                     \
            const char* p = Bl + c * 16384 + nt * 512;                       \
            int4 lo = *reinterpret_cast<const int4*>(p);                     \
            int4 h4 = *reinterpret_cast<const int4*>(p + 4096);              \
            bfr[nt] = mkop(lo, h4);                                          \
        }                                                                    \
        _Pragma("unroll")                                                    \
        for (int mt = 0; mt < 2; ++mt)                                       \
            _Pragma("unroll")                                                \
            for (int nt = 0; nt < 4; ++nt)                                   \
                acc[mt][nt] = __builtin_amdgcn_mfma_scale_f32_32x32x64_f8f6f4(\
                    aA[c][mt], bfr[nt], acc[mt][nt], 0, 0, 0, 127u, 0, 127u);\
    }                                                                        \
    __builtin_amdgcn_s_setprio(0);

// Kernel 2 (MEGA): blocks [0,256) = fp32-exact diagonal argmax; blocks
// [256, 1280) = MX-scaled FP8 MFMA GEMM, persistent-B: each block stages one
// 64KB B panel ONCE and sweeps 6-7 A-tiles (t = sub + 16*i). Per tile the
// rowmax is finished in-wave (shfl_xor allreduce over cols; max = exact) and
// stored to rmg (plain dword stores, no atomics) - B panel never overwritten.
__global__ __launch_bounds__(256, 2)
void filip_mega(const char* __restrict__ t1q, const char* __restrict__ t2q,
                const float* __restrict__ t1, const float* __restrict__ t2,
                const float* __restrict__ inv1, const float* __restrict__ inv2,
                unsigned long long* __restrict__ parts,
                float* __restrict__ rmg,
                float* __restrict__ out)
{
    __shared__ __align__(16) char smem[65536];
    const int bid = blockIdx.x;
    const int tid = threadIdx.x;

    if (bid >= 256) {
        // =================== MX FP8 persistent-B GEMM path ===================
        int n = bid - 256;                      // 0..1023
        int x = n & 7, j = n >> 3;              // j 0..127
        const int b2  = x * 8 + (j >> 4);       // 0..63 (16 blocks share a panel, same XCD)
        const int sub = j & 15;                 // 0..15

        const int lane = tid & 63, wave = tid >> 6;
        const int wr = wave >> 1, wc = wave & 1;
        const int ln = lane & 31, hi = lane >> 5;

        const char* Ag = t1q + hi * 4096 + (wr * 64 + ln) * 16;
        const char* Bg = t2q + (size_t)b2 * 65536;

        // stage full B panel (64KB MX fragment-linear image) ONCE
        #pragma unroll
        for (int i = 0; i < 16; ++i) {
            *reinterpret_cast<ulonglong2*>(smem + i * 4096 + tid * 16) =
                *reinterpret_cast<const ulonglong2*>(Bg + i * 4096 + tid * 16);
        }
        __syncthreads();   // B panel complete

        const char* Bl = smem + hi * 8192 + wc * 2048 + ln * 16;
        v8i aA[4][2];
        f32x16 acc[2][4];

        for (int t = sub; t < 98; t += 16) {
            LOADA((size_t)t * 32768)
            ZEROACC
            KLOOP
            // in-wave rowmax finish: fold nt, then allreduce over 32 cols
            // (shfl offsets 1..16 stay within hi-halves; max is order-free).
            float rm[2][16];
            #pragma unroll
            for (int mt = 0; mt < 2; ++mt)
                #pragma unroll
                for (int r = 0; r < 16; ++r) {
                    float m = fmaxf(fmaxf(acc[mt][0][r], acc[mt][1][r]),
                                    fmaxf(acc[mt][2][r], acc[mt][3][r]));
                    #pragma unroll
                    for (int off = 1; off < 32; off <<= 1)
                        m = fmaxf(m, __shfl_xor(m, off, 64));
                    rm[mt][r] = m;
                }
            // lanes 0 and 32 store their hi-half's 32 complete row-maxes.
            // rmg layout [t][wc][row][b2] -> reduce kernel is b2-coalesced.
            if ((lane & 31) == 0) {
                #pragma unroll
                for (int mt = 0; mt < 2; ++mt)
                    #pragma unroll
                    for (int r = 0; r < 16; ++r) {
                        int row = wr * 64 + mt * 32 + (r & 3) + 8 * (r >> 2) + 4 * hi;
                        rmg[((size_t)t * 2 + wc) * 8192 + row * 64 + b2] = rm[mt][r];
                    }
            }
        }
        return;
    }

    // =================== fp32-exact diagonal path ===================
    {
        const int q = bid & 3;             // 0..3 (row quarter)
        const int b = bid >> 2;            // 0..63
        const int r0 = q * 49;
        const int tx = tid & 15, ty = tid >> 4;

        float* As = reinterpret_cast<float*>(smem);
        float* Bs = As + 2176;
        unsigned long long* colP = reinterpret_cast<unsigned long long*>(smem);

        const float* Ap = t1 + (size_t)b * NP * ND;
        const float* Bp = t2 + (size_t)b * NP * ND;
        const float* ia = inv1 + b * NP;
        const float* ib = inv2 + b * NP;

        float acc[4][4][4];
        #pragma unroll
        for (int i = 0; i < 4; ++i)
            #pragma unroll
            for (int j = 0; j < 4; ++j)
                #pragma unroll
                for (int l = 0; l < 4; ++l) acc[i][j][l] = 0.0f;

        for (int kc = 0; kc < 8; ++kc) {
            __syncthreads();
            #pragma unroll
            for (int i = 0; i < 2; ++i) {
                int f4 = tid + 256 * i;            // 0..511
                int row = f4 >> 3, k4 = f4 & 7;
                float4 v = make_float4(0.f, 0.f, 0.f, 0.f);
                if (row < 49) {
                    v = *reinterpret_cast<const float4*>(Ap + (size_t)(r0 + row) * ND + kc * 32 + 4 * k4);
                    float s = ia[r0 + row];
                    v.x *= s; v.y *= s; v.z *= s; v.w *= s;
                }
                As[(4 * k4 + 0) * 68 + row] = v.x;
                As[(4 * k4 + 1) * 68 + row] = v.y;
                As[(4 * k4 + 2) * 68 + row] = v.z;
                As[(4 * k4 + 3) * 68 + row] = v.w;
            }
            #pragma unroll
            for (int i = 0; i < 8; ++i) {
                int f4 = tid + 256 * i;            // 0..2047
                int col = f4 >> 3, k4 = f4 & 7;
                float4 v = make_float4(0.f, 0.f, 0.f, 0.f);
                if (col < NP) {
                    v = *reinterpret_cast<const float4*>(Bp + (size_t)col * ND + kc * 32 + 4 * k4);
                    float s = ib[col];
                    v.x *= s; v.y *= s; v.z *= s; v.w *= s;
                }
                Bs[(4 * k4 + 0) * 260 + col] = v.x;
                Bs[(4 * k4 + 1) * 260 + col] = v.y;
                Bs[(4 * k4 + 2) * 260 + col] = v.z;
                Bs[(4 * k4 + 3) * 260 + col] = v.w;
            }
            __syncthreads();
            #pragma unroll 4
            for (int k = 0; k < 32; ++k) {
                float a0 = As[k * 68 + 4 * ty + 0];
                float a1 = As[k * 68 + 4 * ty + 1];
                float a2 = As[k * 68 + 4 * ty + 2];
                float a3 = As[k * 68 + 4 * ty + 3];
                float4 bq[4];
                #pragma unroll
                for (int j = 0; j < 4; ++j)
                    bq[j] = *reinterpret_cast<const float4*>(&Bs[k * 260 + 4 * tx + 64 * j]);
                #pragma unroll
                for (int j = 0; j < 4; ++j) {
                    acc[0][j][0] = fmaf(a0, bq[j].x, acc[0][j][0]);
                    acc[0][j][1] = fmaf(a0, bq[j].y, acc[0][j][1]);
                    acc[0][j][2] = fmaf(a0, bq[j].z, acc[0][j][2]);
                    acc[0][j][3] = fmaf(a0, bq[j].w, acc[0][j][3]);
                    acc[1][j][0] = fmaf(a1, bq[j].x, acc[1][j][0]);
                    acc[1][j][1] = fmaf(a1, bq[j].y, acc[1][j][1]);
                    acc[1][j][2] = fmaf(a1, bq[j].z, acc[1][j][2]);
                    acc[1][j][3] = fmaf(a1, bq[j].w, acc[1][j][3]);
                    acc[2][j][0] = fmaf(a2, bq[j].x, acc[2][j][0]);
                    acc[2][j][1] = fmaf(a2, bq[j].y, acc[2][j][1]);
                    acc[2][j][2] = fmaf(a2, bq[j].z, acc[2][j][2]);
                    acc[2][j][3] = fmaf(a2, bq[j].w, acc[2][j][3]);
                    acc[3][j][0] = fmaf(a3, bq[j].x, acc[3][j][0]);
                    acc[3][j][1] = fmaf(a3, bq[j].y, acc[3][j][1]);
                    acc[3][j][2] = fmaf(a3, bq[j].z, acc[3][j][2]);
                    acc[3][j][3] = fmaf(a3, bq[j].w, acc[3][j][3]);
                }
            }
        }

        // row argmax (idx_to_keep1_2)
        #pragma unroll
        for (int i = 0; i < 4; ++i) {
            unsigned long long best = 0ull;
            #pragma unroll
            for (int j = 0; j < 4; ++j)
                #pragma unroll
                for (int l = 0; l < 4; ++l) {
                    int c = 64 * j + 4 * tx + l;
                    if (c < NP) {
                        unsigned long long p = packVI(acc[i][j][l], c);
                        if (p > best) best = p;
                    }
                }
            #pragma unroll
            for (int off = 1; off < 16; off <<= 1) {
                unsigned long long o = __shfl_xor(best, off, 16);
                if (o > best) best = o;
            }
            int rl = 4 * ty + i;
            if (tx == 0 && rl < 49)
                out[1 + b * NP + r0 + rl] = (float)(unsigned int)(~best);
        }

        // col argmax partials (idx_to_keep2_1)
        __syncthreads();
        #pragma unroll
        for (int j = 0; j < 4; ++j)
            #pragma unroll
            for (int l = 0; l < 4; ++l) {
                unsigned long long best = 0ull;
                #pragma unroll
                for (int i = 0; i < 4; ++i) {
                    int rl = 4 * ty + i;
                    if (rl < 49) {
                        unsigned long long p = packVI(acc[i][j][l], r0 + rl);
                        if (p > best) best = p;
                    }
                }
                colP[ty * 256 + 64 * j + 4 * tx + l] = best;
            }
        __syncthreads();
        {
            unsigned long long best = 0ull;
            #pragma unroll
            for (int y = 0; y < 16; ++y) {
                unsigned long long o = colP[y * 256 + tid];
                if (o > best) best = o;
            }
            if (tid < NP) parts[(b * 4 + q) * NP + tid] = best;
        }
    }
}

// Kernel 3: deterministic rowmax reduction -> sim12. Block b1, thread b2.
// Folds wc halves (max) and sums rows p=0..195 ascending; b2-coalesced loads.
__global__ void filip_rsum(const float* __restrict__ rmg,
                           float* __restrict__ sim12) {
    int b1 = blockIdx.x;       // 0..63
    int b2 = threadIdx.x;      // 0..63
    float s = 0.0f;
    for (int p = 0; p < NP; ++p) {
        int g = b1 * NP + p;
        int t = g >> 7, row = g & 127;
        const float* base = rmg + ((size_t)t * 2) * 8192 + row * 64 + b2;
        s += fmaxf(base[0], base[8192]);
    }
    sim12[b1 * NB + b2] = s;
}

// Kernel 4: merged fin (blocks 0..48) + loss (block 49).
__global__ void filip_finloss(const unsigned long long* __restrict__ parts,
                              const float* __restrict__ sim12,
                              float* __restrict__ out) {
    if (blockIdx.x < 49) {
        int id = blockIdx.x * 256 + threadIdx.x;   // 49*256 = 12544
        int b = id / NP, c = id - b * NP;
        unsigned long long best = 0ull;
        #pragma unroll
        for (int qq = 0; qq < 4; ++qq) {
            unsigned long long o = parts[(b * 4 + qq) * NP + c];
            if (o > best) best = o;
        }
        out[1 + NBP + id] = (float)(unsigned int)(~best);
    } else if (threadIdx.x < 64) {
        int i = threadIdx.x;  // 0..63
        const float SC = 10.0f / 196.0f;
        const float* row = sim12 + i * NB;
        float mx = -3.0e38f;
        for (int j = 0; j < NB; ++j) mx = fmaxf(mx, row[j] * SC);
        float s = 0.0f;
        for (int j = 0; j < NB; ++j) s += expf(row[j] * SC - mx);
        float lse = mx + logf(s);
        float li = lse - row[i] * SC;
        #pragma unroll
        for (int off = 32; off > 0; off >>= 1)
            li += __shfl_xor(li, off, 64);
        if (i == 0) out[0] = li / 64.0f;
    }
}

// ===========================================================================
// FALLBACK PATH (verbatim round-2, known-passing) — used if ws too small
// ===========================================================================
__global__ void filip_norms(const float* __restrict__ t1,
                            const float* __restrict__ t2,
                            float* __restrict__ inv1,
                            float* __restrict__ inv2,
                            float* __restrict__ sim12) {
    int row = blockIdx.x;
    int lane = threadIdx.x;
    if (row < NB) sim12[row * NB + lane] = 0.0f;
    const float* src; float* dst; int r;
    if (row < NBP) { src = t1; dst = inv1; r = row; }
    else           { src = t2; dst = inv2; r = row - NBP; }
    float4 v = reinterpret_cast<const float4*>(src + (size_t)r * ND)[lane];
    float ss = v.x * v.x + v.y * v.y + v.z * v.z + v.w * v.w;
    #pragma unroll
    for (int off = 32; off > 0; off >>= 1)
        ss += __shfl_xor(ss, off, 64);
    if (lane == 0)
        dst[r] = 1.0f / fmaxf(sqrtf(ss), 1e-12f);
}

__device__ __forceinline__ v8bf cvt8(float4 a, float4 b, float s) {
    v8bf v;
    v[0] = (__bf16)(a.x * s); v[1] = (__bf16)(a.y * s);
    v[2] = (__bf16)(a.z * s); v[3] = (__bf16)(a.w * s);
    v[4] = (__bf16)(b.x * s); v[5] = (__bf16)(b.y * s);
    v[6] = (__bf16)(b.z * s); v[7] = (__bf16)(b.w * s);
    return v;
}

#define BKF 64
__global__ __launch_bounds__(256, 2)
void filip_mfma(const float* __restrict__ t1, const float* __restrict__ t2,
                const float* __restrict__ inv1, const float* __restrict__ inv2,
                float* __restrict__ sim12)
{
    __shared__ unsigned short Asb[BM * BKF];
    __shared__ unsigned short Bsb[BN * BKF];
    __shared__ float rmx[2][BM];

    const int bRow = blockIdx.x;
    const int b2   = blockIdx.y;
    const int tid  = threadIdx.x;
    const int lane = tid & 63, wave = tid >> 6;
    const int wr = wave >> 1, wc = wave & 1;
    const int ln = lane & 31, hi = lane >> 5;

    const float* Abase = t1 + (size_t)bRow * BM * ND;
    const float* Bbase = t2 + (size_t)b2 * NP * ND;

    f32x16 acc[2][4];
    #pragma unroll
    for (int mt = 0; mt < 2; ++mt)
        #pragma unroll
        for (int nt = 0; nt < 4; ++nt)
            #pragma unroll
            for (int r = 0; r < 16; ++r) acc[mt][nt][r] = 0.0f;

    for (int kc = 0; kc < 4; ++kc) {
        __syncthreads();
        #pragma unroll
        for (int i = 0; i < 4; ++i) {
            int flat = (i * 256 + tid) * 8;
            int r = flat >> 6, k0 = flat & 63;
            const float* gp = Abase + (size_t)r * ND + kc * BKF + k0;
            float4 f0 = *reinterpret_cast<const float4*>(gp);
            float4 f1 = *reinterpret_cast<const float4*>(gp + 4);
            float s = inv1[bRow * BM + r];
            v8bf v = cvt8(f0, f1, s);
            int off = r * 128 + ((k0 * 2) ^ ((r & 7) << 4));
            *reinterpret_cast<v8bf*>(reinterpret_cast<char*>(Asb) + off) = v;
        }
        #pragma unroll
        for (int i = 0; i < 8; ++i) {
            int flat = (i * 256 + tid) * 8;
            int r = flat >> 6, k0 = flat & 63;
            v8bf v;
            if (r < NP) {
                const float* gp = Bbase + (size_t)r * ND + kc * BKF + k0;
                float4 f0 = *reinterpret_cast<const float4*>(gp);
                float4 f1 = *reinterpret_cast<const float4*>(gp + 4);
                float s = inv2[b2 * NP + r];
                v = cvt8(f0, f1, s);
            } else {
                #pragma unroll
                for (int j = 0; j < 8; ++j) v[j] = (__bf16)0.0f;
            }
            int off = r * 128 + ((k0 * 2) ^ ((r & 7) << 4));
            *reinterpret_cast<v8bf*>(reinterpret_cast<char*>(Bsb) + off) = v;
        }
        __syncthreads();
        #pragma unroll
        for (int ks = 0; ks < 4; ++ks) {
            const int kb = ks * 32 + hi * 16;
            v8bf af[2], bfr[4];
            #pragma unroll
            for (int mt = 0; mt < 2; ++mt) {
                int r = wr * 64 + mt * 32 + ln;
                af[mt] = *reinterpret_cast<const v8bf*>(
                    reinterpret_cast<const char*>(Asb) + r * 128 + (kb ^ ((r & 7) << 4)));
            }
            #pragma unroll
            for (int nt = 0; nt < 4; ++nt) {
                int c = wc * 128 + nt * 32 + ln;
                bfr[nt] = *reinterpret_cast<const v8bf*>(
                    reinterpret_cast<const char*>(Bsb) + c * 128 + (kb ^ ((c & 7) << 4)));
            }
            #pragma unroll
            for (int mt = 0; mt < 2; ++mt)
                #pragma unroll
                for (int nt = 0; nt < 4; ++nt)
                    acc[mt][nt] = __builtin_amdgcn_mfma_f32_32x32x16_bf16(
                        af[mt], bfr[nt], acc[mt][nt], 0, 0, 0);
        }
    }

    #pragma unroll
    for (int mt = 0; mt < 2; ++mt) {
        float t[16];
        #pragma unroll
        for (int r = 0; r < 16; ++r) {
            float m = fmaxf(fmaxf(acc[mt][0][r], acc[mt][1][r]),
                            fmaxf(acc[mt][2][r], acc[mt][3][r]));
            #pragma unroll
            for (int off = 1; off <= 16; off <<= 1)
                m = fmaxf(m, __shfl_xor(m, off, 64));
            t[r] = m;
        }
        if (ln == 0) {
            #pragma unroll
            for (int r = 0; r < 16; ++r) {
                int row = wr * 64 + mt * 32 + (r & 3) + 8 * (r >> 2) + 4 * hi;
                rmx[wc][row] = t[r];
            }
        }
    }
    __syncthreads();
    if (tid < BM) {
        float m = fmaxf(rmx[0][tid], rmx[1][tid]);
        int grow = bRow * BM + tid;
        int b1 = grow / NP;
        int fb = (bRow * BM) / NP;
        float v0 = (b1 == fb) ? m : 0.0f;
        float v1 = (b1 != fb) ? m : 0.0f;
        #pragma unroll
        for (int off = 1; off < 64; off <<= 1) {
            v0 += __shfl_xor(v0, off, 64);
            v1 += __shfl_xor(v1, off, 64);
        }
        if (lane == 0) {
            atomicAdd(&sim12[fb * NB + b2], v0);
            int lb = (bRow * BM + BM - 1) / NP;
            if (lb != fb) atomicAdd(&sim12[lb * NB + b2], v1);
        }
    }
}

__global__ __launch_bounds__(256)
void filip_diag(const float* __restrict__ t1, const float* __restrict__ t2,
                const float* __restrict__ inv1, const float* __restrict__ inv2,
                float* __restrict__ out)
{
    const int b = blockIdx.x;
    const int tid = threadIdx.x;
    const int tx = tid & 15, ty = tid >> 4;

    __shared__ float As2[16][209];
    __shared__ float Bs2[16][65];
    __shared__ float colV[16][65];
    __shared__ int   colI[16][65];

    const float* Ap = t1 + (size_t)b * NP * ND;
    const float* Bp = t2 + (size_t)b * NP * ND;
    const float* ia = inv1 + b * NP;
    const float* ib = inv2 + b * NP;

    float rmax[13];
    int   ridx[13];
    #pragma unroll
    for (int m = 0; m < 13; ++m) { rmax[m] = -3.0e38f; ridx[m] = 1 << 30; }

    for (int tile = 0; tile < 4; ++tile) {
        float acc[13][4];
        #pragma unroll
        for (int m = 0; m < 13; ++m)
            #pragma unroll
            for (int n = 0; n < 4; ++n) acc[m][n] = 0.0f;

        for (int kk = 0; kk < 16; ++kk) {
            __syncthreads();
            #pragma unroll
            for (int i = 0; i < 13; ++i) {
                int e = tid + 256 * i;
                int p1 = e >> 4, k = e & 15;
                float v = 0.0f;
                if (p1 < NP) v = Ap[p1 * ND + kk * 16 + k] * ia[p1];
                As2[k][p1] = v;
            }
            #pragma unroll
            for (int i = 0; i < 4; ++i) {
                int e = tid + 256 * i;
                int pl = e >> 4, k = e & 15;
                int p2 = tile * 64 + pl;
                float v = 0.0f;
                if (p2 < NP) v = Bp[p2 * ND + kk * 16 + k] * ib[p2];
                Bs2[k][pl] = v;
            }
            __syncthreads();
            #pragma unroll 4
            for (int k = 0; k < 16; ++k) {
                float a[13], bq[4];
                #pragma unroll
                for (int m = 0; m < 13; ++m) a[m] = As2[k][ty + 16 * m];
                #pragma unroll
                for (int n = 0; n < 4; ++n) bq[n] = Bs2[k][tx + 16 * n];
                #pragma unroll
                for (int m = 0; m < 13; ++m)
                    #pragma unroll
                    for (int n = 0; n < 4; ++n)
                        acc[m][n] = fmaf(a[m], bq[n], acc[m][n]);
            }
        }

        #pragma unroll
        for (int n = 0; n < 4; ++n) {
            int c = tile * 64 + tx + 16 * n;
            if (c < NP) {
                #pragma unroll
                for (int m = 0; m < 13; ++m) {
                    float v = acc[m][n];
                    if (v > rmax[m] || (v == rmax[m] && c < ridx[m])) {
                        rmax[m] = v; ridx[m] = c;
                    }
                }
            }
        }

        #pragma unroll
        for (int n = 0; n < 4; ++n) {
            float bv = -3.0e38f; int bi = 1 << 30;
            #pragma unroll
            for (int m = 0; m < 13; ++m) {
                int row = ty + 16 * m;
                if (row < NP) {
                    float v = acc[m][n];
                    if (v > bv || (v == bv && row < bi)) { bv = v; bi = row; }
                }
            }
            colV[ty][tx + 16 * n] = bv;
            colI[ty][tx + 16 * n] = bi;
        }
        __syncthreads();
        if (tid < 64) {
            int c = tile * 64 + tid;
            if (c < NP) {
                float bv = -3.0e38f; int bi = 1 << 30;
                #pragma unroll
                for (int y = 0; y < 16; ++y) {
                    float v = colV[y][tid]; int i2 = colI[y][tid];
                    if (v > bv || (v == bv && i2 < bi)) { bv = v; bi = i2; }
                }
                out[1 + NBP + b * NP + c] = (float)bi;
            }
        }
        __syncthreads();
    }

    #pragma unroll
    for (int m = 0; m < 13; ++m) {
        float v = rmax[m]; int ix = ridx[m];
        #pragma unroll
        for (int off = 1; off < 16; off <<= 1) {
            float ov = __shfl_xor(v, off, 16);
            int   oi = __shfl_xor(ix, off, 16);
            if (ov > v || (ov == v && oi < ix)) { v = ov; ix = oi; }
        }
        rmax[m] = v; ridx[m] = ix;
    }
    if (tx == 0) {
        #pragma unroll
        for (int m = 0; m < 13; ++m) {
            int row = ty + 16 * m;
            if (row < NP) out[1 + b * NP + row] = (float)ridx[m];
        }
    }
}

__global__ void filip_loss(const float* __restrict__ sim12,
                           float* __restrict__ out) {
    int i = threadIdx.x;  // 0..63
    const float SC = 10.0f / 196.0f;
    const float* row = sim12 + i * NB;
    float mx = -3.0e38f;
    for (int j = 0; j < NB; ++j) mx = fmaxf(mx, row[j] * SC);
    float s = 0.0f;
    for (int j = 0; j < NB; ++j) s += expf(row[j] * SC - mx);
    float lse = mx + logf(s);
    float li = lse - row[i] * SC;
    #pragma unroll
    for (int off = 32; off > 0; off >>= 1)
        li += __shfl_xor(li, off, 64);
    if (i == 0) out[0] = li / 64.0f;
}

// ---------------------------------------------------------------------------
extern "C" void kernel_launch(void* const* d_in, const int* in_sizes, int n_in,
                              void* d_out, int out_size, void* d_ws, size_t ws_size,
                              hipStream_t stream) {
    const float* t1 = (const float*)d_in[0];
    const float* t2 = (const float*)d_in[1];
    float* out = (float*)d_out;
    float* ws  = (float*)d_ws;

    float* inv1  = ws;
    float* inv2  = ws + NBP;
    float* sim12 = ws + 2 * NBP;

    if (ws_size >= (size_t)WS_NEED) {
        char* t1q = (char*)d_ws + WS_T1Q;
        char* t2q = (char*)d_ws + WS_T2Q;
        unsigned long long* parts = (unsigned long long*)((char*)d_ws + WS_PARTS);
        float* rmg = (float*)((char*)d_ws + WS_RMG);

        filip_prep8<<<(NBP + NB * 256) / 4, 256, 0, stream>>>(t1, t2, inv1, inv2, sim12, t1q, t2q);
        filip_mega<<<256 + 1024, 256, 0, stream>>>(t1q, t2q, t1, t2, inv1, inv2, parts, rmg, out);
        filip_rsum<<<NB, NB, 0, stream>>>(rmg, sim12);
        filip_finloss<<<50, 256, 0, stream>>>(parts, sim12, out);
    } else {
        filip_norms<<<2 * NBP, 64, 0, stream>>>(t1, t2, inv1, inv2, sim12);
        filip_mfma<<<dim3(98, NB), 256, 0, stream>>>(t1, t2, inv1, inv2, sim12);
        filip_diag<<<NB, 256, 0, stream>>>(t1, t2, inv1, inv2, out);
        filip_loss<<<1, 64, 0, stream>>>(sim12, out);
    }
}

// Round 23
// 104.803 us; speedup vs baseline: 1.8843x; 1.8843x over previous
//
#include <hip/hip_runtime.h>
#include <math.h>

#define NB 64
#define NP 196
#define ND 256
#define NBP (NB * NP)   // 12544

typedef __bf16 v8bf __attribute__((ext_vector_type(8)));
typedef float f32x16 __attribute__((ext_vector_type(16)));
typedef int v8i __attribute__((ext_vector_type(8)));

// ws layout (fast path), bytes:
//   inv1   @ 0        : 12544 f32
//   inv2   @ 50176    : 12544 f32
//   sim12  @ 100352   : 4096  f32
//   t1q    @ 116736   : 98 tiles  x fp8 MX fragment-linear [chunk4][hi2][half2][row128][16B] = 3211264 B
//   t2q    @ 3328000  : 64 panels x fp8 MX fragment-linear [chunk4][hi2][half2][col256][16B] = 4194304 B
//   parts  @ 7522304  : 64*4*196 u64 = 401408 B
#define WS_T1Q    116736
#define WS_T2Q    3328000
#define WS_PARTS  7522304
#define WS_NEED   7923712

// ---------------------------------------------------------------------------
// packed (value,index) for argmax with np first-occurrence tie-break
// ---------------------------------------------------------------------------
__device__ __forceinline__ unsigned int fmono(float v) {
    unsigned int u = __float_as_uint(v);
    return (u & 0x80000000u) ? ~u : (u | 0x80000000u);
}
__device__ __forceinline__ unsigned long long packVI(float v, int idx) {
    return ((unsigned long long)fmono(v) << 32) | (unsigned int)(~idx);
}

__device__ __forceinline__ v8i mkop(int4 lo, int4 hi) {
    v8i r;
    r[0] = lo.x; r[1] = lo.y; r[2] = lo.z; r[3] = lo.w;
    r[4] = hi.x; r[5] = hi.y; r[6] = hi.z; r[7] = hi.w;
    return r;
}

// ===========================================================================
// FAST PATH
// ===========================================================================

// Kernel 1: per-row norm -> inv arrays; write normalized FP8 (e4m3) in MX
// fragment-linear layout for K=64 scaled MFMA. Lane L holds k = 4L..4L+3:
//   chunk=(L>>4), hi=(L>>3)&1, half=(L>>2)&1, j0=(L&3)*4.
__global__ __launch_bounds__(256)
void filip_prep8(const float* __restrict__ t1, const float* __restrict__ t2,
                 float* __restrict__ inv1, float* __restrict__ inv2,
                 float* __restrict__ sim12,
                 char* __restrict__ t1q, char* __restrict__ t2q) {
    const int tid = threadIdx.x;
    if (blockIdx.x == 0) {
        float4 z = make_float4(0.f, 0.f, 0.f, 0.f);
        float4* s4 = reinterpret_cast<float4*>(sim12);
        #pragma unroll
        for (int j = 0; j < 4; ++j) s4[tid * 4 + j] = z;
    }
    int id = blockIdx.x * 4 + (tid >> 6);   // 0 .. NBP + NB*256 - 1
    int L = tid & 63;
    int chunk = L >> 4, hi = (L >> 3) & 1, half = (L >> 2) & 1, j0 = (L & 3) * 4;
    if (id < NBP) {
        const float* src = t1 + (size_t)id * ND;
        float4 v = reinterpret_cast<const float4*>(src)[L];
        float ss = v.x * v.x + v.y * v.y + v.z * v.z + v.w * v.w;
        #pragma unroll
        for (int off = 32; off > 0; off >>= 1) ss += __shfl_xor(ss, off, 64);
        float inv = 1.0f / fmaxf(sqrtf(ss), 1e-12f);
        if (L == 0) inv1[id] = inv;
        int w0 = __builtin_amdgcn_cvt_pk_fp8_f32(v.x * inv, v.y * inv, 0, false);
        int w  = __builtin_amdgcn_cvt_pk_fp8_f32(v.z * inv, v.w * inv, w0, true);
        int t = id >> 7, r = id & 127;
        *reinterpret_cast<int*>(t1q + (size_t)t * 32768 + chunk * 8192 + hi * 4096
                                + half * 2048 + r * 16 + j0) = w;
    } else {
        int pid = id - NBP;          // 0..16383
        int b2 = pid >> 8, c = pid & 255;
        char* dst = t2q + (size_t)b2 * 65536 + chunk * 16384 + hi * 8192
                    + half * 4096 + c * 16 + j0;
        if (c < NP) {
            const float* src = t2 + (size_t)(b2 * NP + c) * ND;
            float4 v = reinterpret_cast<const float4*>(src)[L];
            float ss = v.x * v.x + v.y * v.y + v.z * v.z + v.w * v.w;
            #pragma unroll
            for (int off = 32; off > 0; off >>= 1) ss += __shfl_xor(ss, off, 64);
            float inv = 1.0f / fmaxf(sqrtf(ss), 1e-12f);
            if (L == 0) inv2[b2 * NP + c] = inv;
            int w0 = __builtin_amdgcn_cvt_pk_fp8_f32(v.x * inv, v.y * inv, 0, false);
            int w  = __builtin_amdgcn_cvt_pk_fp8_f32(v.z * inv, v.w * inv, w0, true);
            *reinterpret_cast<int*>(dst) = w;
        } else {
            *reinterpret_cast<int*>(dst) = 0;   // fp8 zeros
        }
    }
}

#define BM 128
#define BN 256

#define LOADA(TOFF)                                                          \
    _Pragma("unroll")                                                        \
    for (int c = 0; c < 4; ++c)                                              \
        _Pragma("unroll")                                                    \
        for (int mt = 0; mt < 2; ++mt) {                                     \
            const char* p = Ag + (TOFF) + c * 8192 + mt * 512;               \
            int4 lo = *reinterpret_cast<const int4*>(p);                     \
            int4 h4 = *reinterpret_cast<const int4*>(p + 2048);              \
            aA[c][mt] = mkop(lo, h4);                                        \
        }

#define ZEROACC                                                              \
    _Pragma("unroll")                                                        \
    for (int mt = 0; mt < 2; ++mt)                                           \
        _Pragma("unroll")                                                    \
        for (int nt = 0; nt < 4; ++nt)                                       \
            _Pragma("unroll")                                                \
            for (int r = 0; r < 16; ++r) acc[mt][nt][r] = 0.0f;

#define KLOOP                                                                \
    __builtin_amdgcn_s_setprio(1);                                           \
    _Pragma("unroll")                                                        \
    for (int c = 0; c < 4; ++c) {                                            \
        v8i bfr[4];                                                          \
        _Pragma("unroll")                                                    \
        for (int nt = 0; nt < 4; ++nt) {                                     \
            const char* p = Bl + c * 16384 + nt * 512;                       \
            int4 lo = *reinterpret_cast<const int4*>(p);                     \
            int4 h4 = *reinterpret_cast<const int4*>(p + 4096);              \
            bfr[nt] = mkop(lo, h4);                                          \
        }                                                                    \
        _Pragma("unroll")                                                    \
        for (int mt = 0; mt < 2; ++mt)                                       \
            _Pragma("unroll")                                                \
            for (int nt = 0; nt < 4; ++nt)                                   \
                acc[mt][nt] = __builtin_amdgcn_mfma_scale_f32_32x32x64_f8f6f4(\
                    aA[c][mt], bfr[nt], acc[mt][nt], 0, 0, 0, 127u, 0, 127u);\
    }                                                                        \
    __builtin_amdgcn_s_setprio(0);

#define FOLDRM(RM)                                                           \
    _Pragma("unroll")                                                        \
    for (int mt = 0; mt < 2; ++mt)                                           \
        _Pragma("unroll")                                                    \
        for (int r = 0; r < 16; ++r)                                         \
            RM[mt][r] = fmaxf(fmaxf(acc[mt][0][r], acc[mt][1][r]),           \
                              fmaxf(acc[mt][2][r], acc[mt][3][r]));

#define EPILOG(RM, BROW)                                                     \
    _Pragma("unroll")                                                        \
    for (int mt = 0; mt < 2; ++mt) {                                         \
        _Pragma("unroll")                                                    \
        for (int r = 0; r < 16; ++r) {                                       \
            int row = wr * 64 + mt * 32 + (r & 3) + 8 * (r >> 2) + 4 * hi;   \
            pmx[row][wc * 32 + ln] = RM[mt][r];                              \
        }                                                                    \
    }                                                                        \
    __syncthreads();                                                         \
    if (tid < BM) {                                                          \
        const float4* prow = reinterpret_cast<const float4*>(pmx[tid]);      \
        float m = -3.0e38f;                                                  \
        _Pragma("unroll")                                                    \
        for (int j = 0; j < 16; ++j) {                                       \
            float4 v = prow[j];                                              \
            m = fmaxf(m, fmaxf(fmaxf(v.x, v.y), fmaxf(v.z, v.w)));           \
        }                                                                    \
        int grow = (BROW) * BM + tid;                                        \
        int b1 = grow / NP;                                                  \
        int fb = ((BROW) * BM) / NP;                                         \
        float v0 = (b1 == fb) ? m : 0.0f;                                    \
        float v1 = (b1 != fb) ? m : 0.0f;                                    \
        _Pragma("unroll")                                                    \
        for (int off = 1; off < 64; off <<= 1) {                             \
            v0 += __shfl_xor(v0, off, 64);                                   \
            v1 += __shfl_xor(v1, off, 64);                                   \
        }                                                                    \
        if (lane == 0) {                                                     \
            atomicAdd(&sim12[fb * NB + b2], v0);                             \
            int lb = ((BROW) * BM + BM - 1) / NP;                            \
            if (lb != fb) atomicAdd(&sim12[lb * NB + b2], v1);               \
        }                                                                    \
    }                                                                        \
    __syncthreads();

// Kernel 2 (MEGA): blocks [0,256) = fp32-exact diagonal argmax (overlaps the
// GEMM); blocks [256, 3392) = MX-scaled FP8 MFMA GEMM: B panel (64KB) staged
// ONCE and reused by TWO 128-row tiles (halves staging traffic); barrier-free
// K-loops; rowmax folded to registers; dual epilogue after all B reads.
__global__ __launch_bounds__(256, 2)
void filip_mega(const char* __restrict__ t1q, const char* __restrict__ t2q,
                float* __restrict__ sim12,
                const float* __restrict__ t1, const float* __restrict__ t2,
                const float* __restrict__ inv1, const float* __restrict__ inv2,
                unsigned long long* __restrict__ parts,
                float* __restrict__ out)
{
    __shared__ __align__(16) char smem[65536];
    const int bid = blockIdx.x;
    const int tid = threadIdx.x;

    if (bid >= 256) {
        // =================== MX FP8 MFMA GEMM path ===================
        int n = bid - 256;                      // 0..3135
        int x = n & 7, local = n >> 3;          // local 0..391
        const int pairT = local >> 3;           // 0..48 (256-row pair)
        const int b2    = x * 8 + (local & 7);  // 0..63

        const int lane = tid & 63, wave = tid >> 6;
        const int wr = wave >> 1, wc = wave & 1;
        const int ln = lane & 31, hi = lane >> 5;

        const char* Ag = t1q + (size_t)(pairT * 2) * 32768
                       + hi * 4096 + (wr * 64 + ln) * 16;
        const char* Bg = t2q + (size_t)b2 * 65536;

        // preload tile-0 A operands (64 VGPR); latency hides under B staging
        v8i aA[4][2];
        LOADA(0)

        // stage full B panel (64KB MX fragment-linear image)
        #pragma unroll
        for (int i = 0; i < 16; ++i) {
            *reinterpret_cast<ulonglong2*>(smem + i * 4096 + tid * 16) =
                *reinterpret_cast<const ulonglong2*>(Bg + i * 4096 + tid * 16);
        }

        f32x16 acc[2][4];
        ZEROACC
        __syncthreads();   // B panel complete (also drains A loads)

        const char* Bl = smem + hi * 8192 + wc * 2048 + ln * 16;
        float rm0[2][16], rm1[2][16];

        // tile 0: K-loop + fold
        KLOOP
        FOLDRM(rm0)

        // tile 1: reload A (same regs, dead after tile-0), re-zero, K-loop
        LOADA(32768)
        ZEROACC
        KLOOP
        FOLDRM(rm1)

        __syncthreads();   // all B reads done before pmx overwrites smem

        // dual rowmax epilogue via LDS transpose (max associative -> exact)
        // C/D layout (shape-determined): col = lane&31, row = (r&3)+8*(r>>2)+4*hi
        float (*pmx)[68] = reinterpret_cast<float (*)[68]>(smem);
        EPILOG(rm0, pairT * 2)
        EPILOG(rm1, pairT * 2 + 1)
        return;
    }

    // =================== fp32-exact diagonal path ===================
    {
        const int q = bid & 3;             // 0..3 (row quarter)
        const int b = bid >> 2;            // 0..63
        const int r0 = q * 49;
        const int tx = tid & 15, ty = tid >> 4;

        float* As = reinterpret_cast<float*>(smem);
        float* Bs = As + 2176;
        unsigned long long* colP = reinterpret_cast<unsigned long long*>(smem);

        const float* Ap = t1 + (size_t)b * NP * ND;
        const float* Bp = t2 + (size_t)b * NP * ND;
        const float* ia = inv1 + b * NP;
        const float* ib = inv2 + b * NP;

        float acc[4][4][4];
        #pragma unroll
        for (int i = 0; i < 4; ++i)
            #pragma unroll
            for (int j = 0; j < 4; ++j)
                #pragma unroll
                for (int l = 0; l < 4; ++l) acc[i][j][l] = 0.0f;

        for (int kc = 0; kc < 8; ++kc) {
            __syncthreads();
            #pragma unroll
            for (int i = 0; i < 2; ++i) {
                int f4 = tid + 256 * i;            // 0..511
                int row = f4 >> 3, k4 = f4 & 7;
                float4 v = make_float4(0.f, 0.f, 0.f, 0.f);
                if (row < 49) {
                    v = *reinterpret_cast<const float4*>(Ap + (size_t)(r0 + row) * ND + kc * 32 + 4 * k4);
                    float s = ia[r0 + row];
                    v.x *= s; v.y *= s; v.z *= s; v.w *= s;
                }
                As[(4 * k4 + 0) * 68 + row] = v.x;
                As[(4 * k4 + 1) * 68 + row] = v.y;
                As[(4 * k4 + 2) * 68 + row] = v.z;
                As[(4 * k4 + 3) * 68 + row] = v.w;
            }
            #pragma unroll
            for (int i = 0; i < 8; ++i) {
                int f4 = tid + 256 * i;            // 0..2047
                int col = f4 >> 3, k4 = f4 & 7;
                float4 v = make_float4(0.f, 0.f, 0.f, 0.f);
                if (col < NP) {
                    v = *reinterpret_cast<const float4*>(Bp + (size_t)col * ND + kc * 32 + 4 * k4);
                    float s = ib[col];
                    v.x *= s; v.y *= s; v.z *= s; v.w *= s;
                }
                Bs[(4 * k4 + 0) * 260 + col] = v.x;
                Bs[(4 * k4 + 1) * 260 + col] = v.y;
                Bs[(4 * k4 + 2) * 260 + col] = v.z;
                Bs[(4 * k4 + 3) * 260 + col] = v.w;
            }
            __syncthreads();
            #pragma unroll 4
            for (int k = 0; k < 32; ++k) {
                float a0 = As[k * 68 + 4 * ty + 0];
                float a1 = As[k * 68 + 4 * ty + 1];
                float a2 = As[k * 68 + 4 * ty + 2];
                float a3 = As[k * 68 + 4 * ty + 3];
                float4 bq[4];
                #pragma unroll
                for (int j = 0; j < 4; ++j)
                    bq[j] = *reinterpret_cast<const float4*>(&Bs[k * 260 + 4 * tx + 64 * j]);
                #pragma unroll
                for (int j = 0; j < 4; ++j) {
                    acc[0][j][0] = fmaf(a0, bq[j].x, acc[0][j][0]);
                    acc[0][j][1] = fmaf(a0, bq[j].y, acc[0][j][1]);
                    acc[0][j][2] = fmaf(a0, bq[j].z, acc[0][j][2]);
                    acc[0][j][3] = fmaf(a0, bq[j].w, acc[0][j][3]);
                    acc[1][j][0] = fmaf(a1, bq[j].x, acc[1][j][0]);
                    acc[1][j][1] = fmaf(a1, bq[j].y, acc[1][j][1]);
                    acc[1][j][2] = fmaf(a1, bq[j].z, acc[1][j][2]);
                    acc[1][j][3] = fmaf(a1, bq[j].w, acc[1][j][3]);
                    acc[2][j][0] = fmaf(a2, bq[j].x, acc[2][j][0]);
                    acc[2][j][1] = fmaf(a2, bq[j].y, acc[2][j][1]);
                    acc[2][j][2] = fmaf(a2, bq[j].z, acc[2][j][2]);
                    acc[2][j][3] = fmaf(a2, bq[j].w, acc[2][j][3]);
                    acc[3][j][0] = fmaf(a3, bq[j].x, acc[3][j][0]);
                    acc[3][j][1] = fmaf(a3, bq[j].y, acc[3][j][1]);
                    acc[3][j][2] = fmaf(a3, bq[j].z, acc[3][j][2]);
                    acc[3][j][3] = fmaf(a3, bq[j].w, acc[3][j][3]);
                }
            }
        }

        // row argmax (idx_to_keep1_2)
        #pragma unroll
        for (int i = 0; i < 4; ++i) {
            unsigned long long best = 0ull;
            #pragma unroll
            for (int j = 0; j < 4; ++j)
                #pragma unroll
                for (int l = 0; l < 4; ++l) {
                    int c = 64 * j + 4 * tx + l;
                    if (c < NP) {
                        unsigned long long p = packVI(acc[i][j][l], c);
                        if (p > best) best = p;
                    }
                }
            #pragma unroll
            for (int off = 1; off < 16; off <<= 1) {
                unsigned long long o = __shfl_xor(best, off, 16);
                if (o > best) best = o;
            }
            int rl = 4 * ty + i;
            if (tx == 0 && rl < 49)
                out[1 + b * NP + r0 + rl] = (float)(unsigned int)(~best);
        }

        // col argmax partials (idx_to_keep2_1)
        __syncthreads();
        #pragma unroll
        for (int j = 0; j < 4; ++j)
            #pragma unroll
            for (int l = 0; l < 4; ++l) {
                unsigned long long best = 0ull;
                #pragma unroll
                for (int i = 0; i < 4; ++i) {
                    int rl = 4 * ty + i;
                    if (rl < 49) {
                        unsigned long long p = packVI(acc[i][j][l], r0 + rl);
                        if (p > best) best = p;
                    }
                }
                colP[ty * 256 + 64 * j + 4 * tx + l] = best;
            }
        __syncthreads();
        {
            unsigned long long best = 0ull;
            #pragma unroll
            for (int y = 0; y < 16; ++y) {
                unsigned long long o = colP[y * 256 + tid];
                if (o > best) best = o;
            }
            if (tid < NP) parts[(b * 4 + q) * NP + tid] = best;
        }
    }
}

// Kernel 3: merged fin (blocks 0..48) + loss (block 49).
__global__ void filip_finloss(const unsigned long long* __restrict__ parts,
                              const float* __restrict__ sim12,
                              float* __restrict__ out) {
    if (blockIdx.x < 49) {
        int id = blockIdx.x * 256 + threadIdx.x;   // 49*256 = 12544
        int b = id / NP, c = id - b * NP;
        unsigned long long best = 0ull;
        #pragma unroll
        for (int qq = 0; qq < 4; ++qq) {
            unsigned long long o = parts[(b * 4 + qq) * NP + c];
            if (o > best) best = o;
        }
        out[1 + NBP + id] = (float)(unsigned int)(~best);
    } else if (threadIdx.x < 64) {
        int i = threadIdx.x;  // 0..63
        const float SC = 10.0f / 196.0f;
        const float* row = sim12 + i * NB;
        float mx = -3.0e38f;
        for (int j = 0; j < NB; ++j) mx = fmaxf(mx, row[j] * SC);
        float s = 0.0f;
        for (int j = 0; j < NB; ++j) s += expf(row[j] * SC - mx);
        float lse = mx + logf(s);
        float li = lse - row[i] * SC;
        #pragma unroll
        for (int off = 32; off > 0; off >>= 1)
            li += __shfl_xor(li, off, 64);
        if (i == 0) out[0] = li / 64.0f;
    }
}

// ===========================================================================
// FALLBACK PATH (verbatim round-2, known-passing) — used if ws too small
// ===========================================================================
__global__ void filip_norms(const float* __restrict__ t1,
                            const float* __restrict__ t2,
                            float* __restrict__ inv1,
                            float* __restrict__ inv2,
                            float* __restrict__ sim12) {
    int row = blockIdx.x;
    int lane = threadIdx.x;
    if (row < NB) sim12[row * NB + lane] = 0.0f;
    const float* src; float* dst; int r;
    if (row < NBP) { src = t1; dst = inv1; r = row; }
    else           { src = t2; dst = inv2; r = row - NBP; }
    float4 v = reinterpret_cast<const float4*>(src + (size_t)r * ND)[lane];
    float ss = v.x * v.x + v.y * v.y + v.z * v.z + v.w * v.w;
    #pragma unroll
    for (int off = 32; off > 0; off >>= 1)
        ss += __shfl_xor(ss, off, 64);
    if (lane == 0)
        dst[r] = 1.0f / fmaxf(sqrtf(ss), 1e-12f);
}

__device__ __forceinline__ v8bf cvt8(float4 a, float4 b, float s) {
    v8bf v;
    v[0] = (__bf16)(a.x * s); v[1] = (__bf16)(a.y * s);
    v[2] = (__bf16)(a.z * s); v[3] = (__bf16)(a.w * s);
    v[4] = (__bf16)(b.x * s); v[5] = (__bf16)(b.y * s);
    v[6] = (__bf16)(b.z * s); v[7] = (__bf16)(b.w * s);
    return v;
}

#define BKF 64
__global__ __launch_bounds__(256, 2)
void filip_mfma(const float* __restrict__ t1, const float* __restrict__ t2,
                const float* __restrict__ inv1, const float* __restrict__ inv2,
                float* __restrict__ sim12)
{
    __shared__ unsigned short Asb[BM * BKF];
    __shared__ unsigned short Bsb[BN * BKF];
    __shared__ float rmx[2][BM];

    const int bRow = blockIdx.x;
    const int b2   = blockIdx.y;
    const int tid  = threadIdx.x;
    const int lane = tid & 63, wave = tid >> 6;
    const int wr = wave >> 1, wc = wave & 1;
    const int ln = lane & 31, hi = lane >> 5;

    const float* Abase = t1 + (size_t)bRow * BM * ND;
    const float* Bbase = t2 + (size_t)b2 * NP * ND;

    f32x16 acc[2][4];
    #pragma unroll
    for (int mt = 0; mt < 2; ++mt)
        #pragma unroll
        for (int nt = 0; nt < 4; ++nt)
            #pragma unroll
            for (int r = 0; r < 16; ++r) acc[mt][nt][r] = 0.0f;

    for (int kc = 0; kc < 4; ++kc) {
        __syncthreads();
        #pragma unroll
        for (int i = 0; i < 4; ++i) {
            int flat = (i * 256 + tid) * 8;
            int r = flat >> 6, k0 = flat & 63;
            const float* gp = Abase + (size_t)r * ND + kc * BKF + k0;
            float4 f0 = *reinterpret_cast<const float4*>(gp);
            float4 f1 = *reinterpret_cast<const float4*>(gp + 4);
            float s = inv1[bRow * BM + r];
            v8bf v = cvt8(f0, f1, s);
            int off = r * 128 + ((k0 * 2) ^ ((r & 7) << 4));
            *reinterpret_cast<v8bf*>(reinterpret_cast<char*>(Asb) + off) = v;
        }
        #pragma unroll
        for (int i = 0; i < 8; ++i) {
            int flat = (i * 256 + tid) * 8;
            int r = flat >> 6, k0 = flat & 63;
            v8bf v;
            if (r < NP) {
                const float* gp = Bbase + (size_t)r * ND + kc * BKF + k0;
                float4 f0 = *reinterpret_cast<const float4*>(gp);
                float4 f1 = *reinterpret_cast<const float4*>(gp + 4);
                float s = inv2[b2 * NP + r];
                v = cvt8(f0, f1, s);
            } else {
                #pragma unroll
                for (int j = 0; j < 8; ++j) v[j] = (__bf16)0.0f;
            }
            int off = r * 128 + ((k0 * 2) ^ ((r & 7) << 4));
            *reinterpret_cast<v8bf*>(reinterpret_cast<char*>(Bsb) + off) = v;
        }
        __syncthreads();
        #pragma unroll
        for (int ks = 0; ks < 4; ++ks) {
            const int kb = ks * 32 + hi * 16;
            v8bf af[2], bfr[4];
            #pragma unroll
            for (int mt = 0; mt < 2; ++mt) {
                int r = wr * 64 + mt * 32 + ln;
                af[mt] = *reinterpret_cast<const v8bf*>(
                    reinterpret_cast<const char*>(Asb) + r * 128 + (kb ^ ((r & 7) << 4)));
            }
            #pragma unroll
            for (int nt = 0; nt < 4; ++nt) {
                int c = wc * 128 + nt * 32 + ln;
                bfr[nt] = *reinterpret_cast<const v8bf*>(
                    reinterpret_cast<const char*>(Bsb) + c * 128 + (kb ^ ((c & 7) << 4)));
            }
            #pragma unroll
            for (int mt = 0; mt < 2; ++mt)
                #pragma unroll
                for (int nt = 0; nt < 4; ++nt)
                    acc[mt][nt] = __builtin_amdgcn_mfma_f32_32x32x16_bf16(
                        af[mt], bfr[nt], acc[mt][nt], 0, 0, 0);
        }
    }

    #pragma unroll
    for (int mt = 0; mt < 2; ++mt) {
        float t[16];
        #pragma unroll
        for (int r = 0; r < 16; ++r) {
            float m = fmaxf(fmaxf(acc[mt][0][r], acc[mt][1][r]),
                            fmaxf(acc[mt][2][r], acc[mt][3][r]));
            #pragma unroll
            for (int off = 1; off <= 16; off <<= 1)
                m = fmaxf(m, __shfl_xor(m, off, 64));
            t[r] = m;
        }
        if (ln == 0) {
            #pragma unroll
            for (int r = 0; r < 16; ++r) {
                int row = wr * 64 + mt * 32 + (r & 3) + 8 * (r >> 2) + 4 * hi;
                rmx[wc][row] = t[r];
            }
        }
    }
    __syncthreads();
    if (tid < BM) {
        float m = fmaxf(rmx[0][tid], rmx[1][tid]);
        int grow = bRow * BM + tid;
        int b1 = grow / NP;
        int fb = (bRow * BM) / NP;
        float v0 = (b1 == fb) ? m : 0.0f;
        float v1 = (b1 != fb) ? m : 0.0f;
        #pragma unroll
        for (int off = 1; off < 64; off <<= 1) {
            v0 += __shfl_xor(v0, off, 64);
            v1 += __shfl_xor(v1, off, 64);
        }
        if (lane == 0) {
            atomicAdd(&sim12[fb * NB + b2], v0);
            int lb = (bRow * BM + BM - 1) / NP;
            if (lb != fb) atomicAdd(&sim12[lb * NB + b2], v1);
        }
    }
}

__global__ __launch_bounds__(256)
void filip_diag(const float* __restrict__ t1, const float* __restrict__ t2,
                const float* __restrict__ inv1, const float* __restrict__ inv2,
                float* __restrict__ out)
{
    const int b = blockIdx.x;
    const int tid = threadIdx.x;
    const int tx = tid & 15, ty = tid >> 4;

    __shared__ float As2[16][209];
    __shared__ float Bs2[16][65];
    __shared__ float colV[16][65];
    __shared__ int   colI[16][65];

    const float* Ap = t1 + (size_t)b * NP * ND;
    const float* Bp = t2 + (size_t)b * NP * ND;
    const float* ia = inv1 + b * NP;
    const float* ib = inv2 + b * NP;

    float rmax[13];
    int   ridx[13];
    #pragma unroll
    for (int m = 0; m < 13; ++m) { rmax[m] = -3.0e38f; ridx[m] = 1 << 30; }

    for (int tile = 0; tile < 4; ++tile) {
        float acc[13][4];
        #pragma unroll
        for (int m = 0; m < 13; ++m)
            #pragma unroll
            for (int n = 0; n < 4; ++n) acc[m][n] = 0.0f;

        for (int kk = 0; kk < 16; ++kk) {
            __syncthreads();
            #pragma unroll
            for (int i = 0; i < 13; ++i) {
                int e = tid + 256 * i;
                int p1 = e >> 4, k = e & 15;
                float v = 0.0f;
                if (p1 < NP) v = Ap[p1 * ND + kk * 16 + k] * ia[p1];
                As2[k][p1] = v;
            }
            #pragma unroll
            for (int i = 0; i < 4; ++i) {
                int e = tid + 256 * i;
                int pl = e >> 4, k = e & 15;
                int p2 = tile * 64 + pl;
                float v = 0.0f;
                if (p2 < NP) v = Bp[p2 * ND + kk * 16 + k] * ib[p2];
                Bs2[k][pl] = v;
            }
            __syncthreads();
            #pragma unroll 4
            for (int k = 0; k < 16; ++k) {
                float a[13], bq[4];
                #pragma unroll
                for (int m = 0; m < 13; ++m) a[m] = As2[k][ty + 16 * m];
                #pragma unroll
                for (int n = 0; n < 4; ++n) bq[n] = Bs2[k][tx + 16 * n];
                #pragma unroll
                for (int m = 0; m < 13; ++m)
                    #pragma unroll
                    for (int n = 0; n < 4; ++n)
                        acc[m][n] = fmaf(a[m], bq[n], acc[m][n]);
            }
        }

        #pragma unroll
        for (int n = 0; n < 4; ++n) {
            int c = tile * 64 + tx + 16 * n;
            if (c < NP) {
                #pragma unroll
                for (int m = 0; m < 13; ++m) {
                    float v = acc[m][n];
                    if (v > rmax[m] || (v == rmax[m] && c < ridx[m])) {
                        rmax[m] = v; ridx[m] = c;
                    }
                }
            }
        }

        #pragma unroll
        for (int n = 0; n < 4; ++n) {
            float bv = -3.0e38f; int bi = 1 << 30;
            #pragma unroll
            for (int m = 0; m < 13; ++m) {
                int row = ty + 16 * m;
                if (row < NP) {
                    float v = acc[m][n];
                    if (v > bv || (v == bv && row < bi)) { bv = v; bi = row; }
                }
            }
            colV[ty][tx + 16 * n] = bv;
            colI[ty][tx + 16 * n] = bi;
        }
        __syncthreads();
        if (tid < 64) {
            int c = tile * 64 + tid;
            if (c < NP) {
                float bv = -3.0e38f; int bi = 1 << 30;
                #pragma unroll
                for (int y = 0; y < 16; ++y) {
                    float v = colV[y][tid]; int i2 = colI[y][tid];
                    if (v > bv || (v == bv && i2 < bi)) { bv = v; bi = i2; }
                }
                out[1 + NBP + b * NP + c] = (float)bi;
            }
        }
        __syncthreads();
    }

    #pragma unroll
    for (int m = 0; m < 13; ++m) {
        float v = rmax[m]; int ix = ridx[m];
        #pragma unroll
        for (int off = 1; off < 16; off <<= 1) {
            float ov = __shfl_xor(v, off, 16);
            int   oi = __shfl_xor(ix, off, 16);
            if (ov > v || (ov == v && oi < ix)) { v = ov; ix = oi; }
        }
        rmax[m] = v; ridx[m] = ix;
    }
    if (tx == 0) {
        #pragma unroll
        for (int m = 0; m < 13; ++m) {
            int row = ty + 16 * m;
            if (row < NP) out[1 + b * NP + row] = (float)ridx[m];
        }
    }
}

__global__ void filip_loss(const float* __restrict__ sim12,
                           float* __restrict__ out) {
    int i = threadIdx.x;  // 0..63
    const float SC = 10.0f / 196.0f;
    const float* row = sim12 + i * NB;
    float mx = -3.0e38f;
    for (int j = 0; j < NB; ++j) mx = fmaxf(mx, row[j] * SC);
    float s = 0.0f;
    for (int j = 0; j < NB; ++j) s += expf(row[j] * SC - mx);
    float lse = mx + logf(s);
    float li = lse - row[i] * SC;
    #pragma unroll
    for (int off = 32; off > 0; off >>= 1)
        li += __shfl_xor(li, off, 64);
    if (i == 0) out[0] = li / 64.0f;
}

// ---------------------------------------------------------------------------
extern "C" void kernel_launch(void* const* d_in, const int* in_sizes, int n_in,
                              void* d_out, int out_size, void* d_ws, size_t ws_size,
                              hipStream_t stream) {
    const float* t1 = (const float*)d_in[0];
    const float* t2 = (const float*)d_in[1];
    float* out = (float*)d_out;
    float* ws  = (float*)d_ws;

    float* inv1  = ws;
    float* inv2  = ws + NBP;
    float* sim12 = ws + 2 * NBP;

    if (ws_size >= (size_t)WS_NEED) {
        char* t1q = (char*)d_ws + WS_T1Q;
        char* t2q = (char*)d_ws + WS_T2Q;
        unsigned long long* parts = (unsigned long long*)((char*)d_ws + WS_PARTS);

        filip_prep8<<<(NBP + NB * 256) / 4, 256, 0, stream>>>(t1, t2, inv1, inv2, sim12, t1q, t2q);
        filip_mega<<<256 + 3136, 256, 0, stream>>>(t1q, t2q, sim12, t1, t2, inv1, inv2, parts, out);
        filip_finloss<<<50, 256, 0, stream>>>(parts, sim12, out);
    } else {
        filip_norms<<<2 * NBP, 64, 0, stream>>>(t1, t2, inv1, inv2, sim12);
        filip_mfma<<<dim3(98, NB), 256, 0, stream>>>(t1, t2, inv1, inv2, sim12);
        filip_diag<<<NB, 256, 0, stream>>>(t1, t2, inv1, inv2, out);
        filip_loss<<<1, 64, 0, stream>>>(sim12, out);
    }
}